// Round 1
// baseline (220.033 us; speedup 1.0000x reference)
//
#include <hip/hip_runtime.h>
#include <hip/hip_bf16.h>
#include <stdint.h>

#define SEQ     2048
#define BATCH   2
#define NHEADS  16
#define HDIM    64
#define DMODEL  1024
#define N3      3072
#define MTOT    (BATCH*SEQ)   // 4096

typedef __attribute__((ext_vector_type(4))) float f32x4;
typedef __attribute__((ext_vector_type(8))) short bf16x8;

static __device__ inline unsigned short f2bf(float f) {
    union { float f; unsigned u; } v; v.f = f;
    unsigned r = (v.u + 0x7fffu + ((v.u >> 16) & 1u)) >> 16;
    return (unsigned short)r;
}

// ---------------- cast x, w_qkv, w_out to bf16 (one fused launch) -------------
// ranges: [0, 4194304) -> x ; [4194304, 7340032) -> w_qkv ; [7340032, 8388608) -> w_out
__global__ void cast_all(const float* __restrict__ x,
                         const float* __restrict__ wqkv,
                         const float* __restrict__ wout,
                         unsigned short* __restrict__ xb,
                         unsigned short* __restrict__ wqkvb,
                         unsigned short* __restrict__ woutb) {
    long i4 = (long)(blockIdx.x * blockDim.x + threadIdx.x) * 4;
    const float* src; unsigned short* dst; long off;
    if (i4 < 4194304L)      { src = x;    dst = xb;    off = i4; }
    else if (i4 < 7340032L) { src = wqkv; dst = wqkvb; off = i4 - 4194304L; }
    else                    { src = wout; dst = woutb; off = i4 - 7340032L; }
    float4 v = *(const float4*)(src + off);
    ushort4 o;
    o.x = f2bf(v.x); o.y = f2bf(v.y); o.z = f2bf(v.z); o.w = f2bf(v.w);
    *(ushort4*)(dst + off) = o;
}

// ---------------- GEMM (NT): C[m,n] = sum_k A[m,k]*B[n,k] + bias[n] ----------
// A: [M][1024] bf16, B: [N][1024] bf16. Block tile 128x128, BK=32, 4 waves 2x2,
// each wave 64x64 via 4x4 grid of 16x16x32 MFMA tiles.
#define BK 32

__global__ __launch_bounds__(256, 2) void gemm_qkv(
    const unsigned short* __restrict__ A,   // xb [4096][1024]
    const unsigned short* __restrict__ B,   // wqkvb [3072][1024]
    const float* __restrict__ bias,         // [3072]
    unsigned short* __restrict__ C)         // qkv bf16 [4096][3072]
{
    __shared__ __align__(16) unsigned short sA[128][BK];
    __shared__ __align__(16) unsigned short sB[128][BK];
    const int tid  = threadIdx.x;
    const int wave = tid >> 6, lane = tid & 63;
    const int quad = lane >> 4, l16 = lane & 15;
    const int wm = wave >> 1, wn = wave & 1;
    const int m0 = blockIdx.x * 128, n0 = blockIdx.y * 128;

    const int srow = tid >> 2;   // 0..63
    const int sseg = tid & 3;    // 0..3, 8 elems (16B) each

    f32x4 acc[4][4];
    const f32x4 zero = {0.f, 0.f, 0.f, 0.f};
    #pragma unroll
    for (int i = 0; i < 4; i++)
        #pragma unroll
        for (int j = 0; j < 4; j++) acc[i][j] = zero;

    for (int k0 = 0; k0 < 1024; k0 += BK) {
        int4 ra0 = *(const int4*)(A + (long)(m0 + srow)      * 1024 + k0 + sseg * 8);
        int4 ra1 = *(const int4*)(A + (long)(m0 + srow + 64) * 1024 + k0 + sseg * 8);
        int4 rb0 = *(const int4*)(B + (long)(n0 + srow)      * 1024 + k0 + sseg * 8);
        int4 rb1 = *(const int4*)(B + (long)(n0 + srow + 64) * 1024 + k0 + sseg * 8);
        __syncthreads();
        *(int4*)(&sA[srow][sseg * 8])      = ra0;
        *(int4*)(&sA[srow + 64][sseg * 8]) = ra1;
        *(int4*)(&sB[srow][sseg * 8])      = rb0;
        *(int4*)(&sB[srow + 64][sseg * 8]) = rb1;
        __syncthreads();
        bf16x8 af[4], bfr[4];
        #pragma unroll
        for (int mt = 0; mt < 4; mt++)
            af[mt] = *(const bf16x8*)(&sA[wm * 64 + mt * 16 + l16][quad * 8]);
        #pragma unroll
        for (int nt = 0; nt < 4; nt++)
            bfr[nt] = *(const bf16x8*)(&sB[wn * 64 + nt * 16 + l16][quad * 8]);
        #pragma unroll
        for (int mt = 0; mt < 4; mt++)
            #pragma unroll
            for (int nt = 0; nt < 4; nt++)
                acc[mt][nt] = __builtin_amdgcn_mfma_f32_16x16x32_bf16(
                    af[mt], bfr[nt], acc[mt][nt], 0, 0, 0);
    }
    #pragma unroll
    for (int nt = 0; nt < 4; nt++) {
        const int n_g = n0 + wn * 64 + nt * 16 + l16;
        const float bv = bias[n_g];
        #pragma unroll
        for (int mt = 0; mt < 4; mt++) {
            #pragma unroll
            for (int r = 0; r < 4; r++) {
                const int m_g = m0 + wm * 64 + mt * 16 + quad * 4 + r;
                C[(long)m_g * N3 + n_g] = f2bf(acc[mt][nt][r] + bv);
            }
        }
    }
}

__global__ __launch_bounds__(256, 2) void gemm_out(
    const unsigned short* __restrict__ A,   // attnb [4096][1024]
    const unsigned short* __restrict__ B,   // woutb [1024][1024]
    const float* __restrict__ bias,         // [1024]
    float* __restrict__ C)                  // d_out fp32 [4096][1024]
{
    __shared__ __align__(16) unsigned short sA[128][BK];
    __shared__ __align__(16) unsigned short sB[128][BK];
    const int tid  = threadIdx.x;
    const int wave = tid >> 6, lane = tid & 63;
    const int quad = lane >> 4, l16 = lane & 15;
    const int wm = wave >> 1, wn = wave & 1;
    const int m0 = blockIdx.x * 128, n0 = blockIdx.y * 128;

    const int srow = tid >> 2;
    const int sseg = tid & 3;

    f32x4 acc[4][4];
    const f32x4 zero = {0.f, 0.f, 0.f, 0.f};
    #pragma unroll
    for (int i = 0; i < 4; i++)
        #pragma unroll
        for (int j = 0; j < 4; j++) acc[i][j] = zero;

    for (int k0 = 0; k0 < 1024; k0 += BK) {
        int4 ra0 = *(const int4*)(A + (long)(m0 + srow)      * 1024 + k0 + sseg * 8);
        int4 ra1 = *(const int4*)(A + (long)(m0 + srow + 64) * 1024 + k0 + sseg * 8);
        int4 rb0 = *(const int4*)(B + (long)(n0 + srow)      * 1024 + k0 + sseg * 8);
        int4 rb1 = *(const int4*)(B + (long)(n0 + srow + 64) * 1024 + k0 + sseg * 8);
        __syncthreads();
        *(int4*)(&sA[srow][sseg * 8])      = ra0;
        *(int4*)(&sA[srow + 64][sseg * 8]) = ra1;
        *(int4*)(&sB[srow][sseg * 8])      = rb0;
        *(int4*)(&sB[srow + 64][sseg * 8]) = rb1;
        __syncthreads();
        bf16x8 af[4], bfr[4];
        #pragma unroll
        for (int mt = 0; mt < 4; mt++)
            af[mt] = *(const bf16x8*)(&sA[wm * 64 + mt * 16 + l16][quad * 8]);
        #pragma unroll
        for (int nt = 0; nt < 4; nt++)
            bfr[nt] = *(const bf16x8*)(&sB[wn * 64 + nt * 16 + l16][quad * 8]);
        #pragma unroll
        for (int mt = 0; mt < 4; mt++)
            #pragma unroll
            for (int nt = 0; nt < 4; nt++)
                acc[mt][nt] = __builtin_amdgcn_mfma_f32_16x16x32_bf16(
                    af[mt], bfr[nt], acc[mt][nt], 0, 0, 0);
    }
    #pragma unroll
    for (int nt = 0; nt < 4; nt++) {
        const int n_g = n0 + wn * 64 + nt * 16 + l16;
        const float bv = bias[n_g];
        #pragma unroll
        for (int mt = 0; mt < 4; mt++) {
            #pragma unroll
            for (int r = 0; r < 4; r++) {
                const int m_g = m0 + wm * 64 + mt * 16 + quad * 4 + r;
                C[(long)m_g * DMODEL + n_g] = acc[mt][nt][r] + bv;
            }
        }
    }
}

// ---------------- flash attention (causal) -----------------------------------
// grid: (32 bh, 32 qtiles). Block = 4 waves; wave w owns Q rows qbase+16w..+15.
// KV tiles of 64 staged in LDS: sK[kv][d], sVt[d][kv]. Online softmax per row.
__global__ __launch_bounds__(256, 2) void attn_kernel(
    const unsigned short* __restrict__ qkv,  // [4096][3072] bf16 (q|k|v)
    unsigned short* __restrict__ attn)       // [4096][1024] bf16
{
    __shared__ __align__(16) unsigned short sK[64][72];
    __shared__ __align__(16) unsigned short sVt[64][72];
    __shared__ __align__(16) unsigned short sP[4][16][72];

    const int tid  = threadIdx.x;
    const int wave = tid >> 6, lane = tid & 63;
    const int quad = lane >> 4, l16 = lane & 15;

    const int bh = blockIdx.x;                     // 0..31
    const int b  = bh >> 4, h = bh & 15;
    const int qtile = (int)gridDim.y - 1 - (int)blockIdx.y;  // big tiles first
    const int qbase = qtile * 64;

    // Q fragments (A-layout: m=l16, k=quad*8+j), d in [0,64) via 2 frags
    bf16x8 qf[2];
    {
        const int qrow = qbase + wave * 16 + l16;
        const unsigned short* qp = qkv + (long)(b * SEQ + qrow) * N3 + h * HDIM;
        qf[0] = *(const bf16x8*)(qp + quad * 8);
        qf[1] = *(const bf16x8*)(qp + 32 + quad * 8);
    }

    const f32x4 zero = {0.f, 0.f, 0.f, 0.f};
    f32x4 Oacc[4];
    #pragma unroll
    for (int nt = 0; nt < 4; nt++) Oacc[nt] = zero;
    float m_i[4], l_i[4];
    #pragma unroll
    for (int r = 0; r < 4; r++) { m_i[r] = -1e30f; l_i[r] = 0.f; }

    const int ntiles = qtile + 1;
    const int qmaxw  = qbase + wave * 16 + 15;

    // staging index precompute
    const int kr = tid >> 3, ksg = tid & 7;   // K: 32 rows x 8 segs (x2 sweeps)
    const int vr = tid >> 2, vds = tid & 3;   // V: 64 rows x 4 dsegs of 16

    for (int t = 0; t < ntiles; ++t) {
        const int kv0 = t * 64;
        // ---- stage K tile [64][64] and V tile transposed [64][64] ----
        const unsigned short* kp = qkv + (long)(b * SEQ + kv0 + kr) * N3 + DMODEL + h * HDIM + ksg * 8;
        int4 kv_a = *(const int4*)kp;
        int4 kv_b = *(const int4*)(kp + 32L * N3);
        const unsigned short* vp = qkv + (long)(b * SEQ + kv0 + vr) * N3 + 2 * DMODEL + h * HDIM + vds * 16;
        int4 v_a = *(const int4*)vp;
        int4 v_b = *(const int4*)(vp + 8);
        __syncthreads();   // previous iteration's compute done
        *(int4*)(&sK[kr][ksg * 8])      = kv_a;
        *(int4*)(&sK[kr + 32][ksg * 8]) = kv_b;
        {
            const unsigned short* va = (const unsigned short*)&v_a;
            const unsigned short* vb = (const unsigned short*)&v_b;
            #pragma unroll
            for (int j = 0; j < 8; j++) sVt[vds * 16 + j][vr]     = va[j];
            #pragma unroll
            for (int j = 0; j < 8; j++) sVt[vds * 16 + 8 + j][vr] = vb[j];
        }
        __syncthreads();

        if (kv0 <= qmaxw) {
            // ---- scores: S = Q K^T (16x64 per wave) ----
            f32x4 sc[4];
            #pragma unroll
            for (int nt = 0; nt < 4; nt++) {
                bf16x8 kf0 = *(const bf16x8*)(&sK[nt * 16 + l16][quad * 8]);
                bf16x8 kf1 = *(const bf16x8*)(&sK[nt * 16 + l16][32 + quad * 8]);
                sc[nt] = __builtin_amdgcn_mfma_f32_16x16x32_bf16(qf[0], kf0, zero, 0, 0, 0);
                sc[nt] = __builtin_amdgcn_mfma_f32_16x16x32_bf16(qf[1], kf1, sc[nt], 0, 0, 0);
            }
            // ---- online softmax (rows: quad*4+r, cols: nt*16+l16) ----
            const int rowg = qbase + wave * 16 + quad * 4;
            #pragma unroll
            for (int r = 0; r < 4; r++) {
                float mx = -1e30f;
                #pragma unroll
                for (int nt = 0; nt < 4; nt++) {
                    const int colg = kv0 + nt * 16 + l16;
                    float s = sc[nt][r] * 0.125f;
                    if (colg > rowg + r) s = -1e30f;
                    sc[nt][r] = s;
                    mx = fmaxf(mx, s);
                }
                #pragma unroll
                for (int off = 1; off < 16; off <<= 1)
                    mx = fmaxf(mx, __shfl_xor(mx, off));
                const float mnew = fmaxf(m_i[r], mx);
                const float alpha = __expf(m_i[r] - mnew);
                float sum = 0.f;
                #pragma unroll
                for (int nt = 0; nt < 4; nt++) {
                    float p = __expf(sc[nt][r] - mnew);
                    sc[nt][r] = p;
                    sum += p;
                }
                #pragma unroll
                for (int off = 1; off < 16; off <<= 1)
                    sum += __shfl_xor(sum, off);
                l_i[r] = l_i[r] * alpha + sum;
                m_i[r] = mnew;
                #pragma unroll
                for (int nt = 0; nt < 4; nt++) Oacc[nt][r] *= alpha;
            }
            // ---- P: C-layout -> A-layout via per-wave LDS round-trip ----
            #pragma unroll
            for (int nt = 0; nt < 4; nt++)
                #pragma unroll
                for (int r = 0; r < 4; r++)
                    sP[wave][quad * 4 + r][nt * 16 + l16] = f2bf(sc[nt][r]);
            bf16x8 pf0 = *(const bf16x8*)(&sP[wave][l16][quad * 8]);
            bf16x8 pf1 = *(const bf16x8*)(&sP[wave][l16][32 + quad * 8]);
            // ---- O += P V ----
            #pragma unroll
            for (int nt = 0; nt < 4; nt++) {
                bf16x8 vf0 = *(const bf16x8*)(&sVt[nt * 16 + l16][quad * 8]);
                bf16x8 vf1 = *(const bf16x8*)(&sVt[nt * 16 + l16][32 + quad * 8]);
                Oacc[nt] = __builtin_amdgcn_mfma_f32_16x16x32_bf16(pf0, vf0, Oacc[nt], 0, 0, 0);
                Oacc[nt] = __builtin_amdgcn_mfma_f32_16x16x32_bf16(pf1, vf1, Oacc[nt], 0, 0, 0);
            }
        }
    }
    // ---- epilogue: attn[b, row, h*64+d] = O / l ----
    const int rowg = qbase + wave * 16 + quad * 4;
    #pragma unroll
    for (int r = 0; r < 4; r++) {
        const float inv = 1.0f / l_i[r];
        #pragma unroll
        for (int nt = 0; nt < 4; nt++)
            attn[(long)(b * SEQ + rowg + r) * DMODEL + h * HDIM + nt * 16 + l16] =
                f2bf(Oacc[nt][r] * inv);
    }
}

// -----------------------------------------------------------------------------
extern "C" void kernel_launch(void* const* d_in, const int* in_sizes, int n_in,
                              void* d_out, int out_size, void* d_ws, size_t ws_size,
                              hipStream_t stream) {
    const float* x    = (const float*)d_in[0];
    const float* wqkv = (const float*)d_in[1];
    const float* bqkv = (const float*)d_in[2];
    const float* wout = (const float*)d_in[3];
    const float* bout = (const float*)d_in[4];

    char* ws = (char*)d_ws;
    unsigned short* xb    = (unsigned short*)(ws);                       //  8.0 MiB
    unsigned short* wqkvb = (unsigned short*)(ws + 8388608);             //  6.0 MiB
    unsigned short* woutb = (unsigned short*)(ws + 14680064);            //  2.0 MiB
    unsigned short* qkvb  = (unsigned short*)(ws + 16777216);            // 24.0 MiB
    unsigned short* attnb = (unsigned short*)(ws + 41943040);            //  8.0 MiB
    // total ws use: 50331648 bytes

    cast_all<<<8192, 256, 0, stream>>>(x, wqkv, wout, xb, wqkvb, woutb);

    dim3 g1(32, 24);   // M/128, N3/128
    gemm_qkv<<<g1, 256, 0, stream>>>(xb, wqkvb, bqkv, qkvb);

    dim3 g2(32, 32);   // bh, qtiles
    attn_kernel<<<g2, 256, 0, stream>>>(qkvb, attnb);

    dim3 g3(32, 8);    // M/128, DMODEL/128
    gemm_out<<<g3, 256, 0, stream>>>(attnb, woutb, bout, (float*)d_out);
}

// Round 2
// 182.268 us; speedup vs baseline: 1.2072x; 1.2072x over previous
//
#include <hip/hip_runtime.h>
#include <hip/hip_bf16.h>
#include <stdint.h>

#define SEQ     2048
#define BATCH   2
#define NHEADS  16
#define HDIM    64
#define DMODEL  1024
#define N3      3072
#define MTOT    (BATCH*SEQ)   // 4096

typedef __attribute__((ext_vector_type(4))) float f32x4;
typedef __attribute__((ext_vector_type(8))) short bf16x8;

static __device__ inline unsigned short f2bf(float f) {
    union { float f; unsigned u; } v; v.f = f;
    unsigned r = (v.u + 0x7fffu + ((v.u >> 16) & 1u)) >> 16;
    return (unsigned short)r;
}

// async global->LDS, 16B per lane. LDS dst must be wave-uniform base + lane*16.
#define GLDS(gp, lp) __builtin_amdgcn_global_load_lds( \
    (const __attribute__((address_space(1))) void*)(gp), \
    (__attribute__((address_space(3))) void*)(lp), 16, 0, 0)

// 16-lane butterfly reductions on the VALU pipe (DPP), no LDS traffic.
static __device__ inline float dpp_max16(float v) {
    v = fmaxf(v, __int_as_float(__builtin_amdgcn_mov_dpp(__float_as_int(v), 0xB1, 0xF, 0xF, true)));  // quad_perm(1,0,3,2)
    v = fmaxf(v, __int_as_float(__builtin_amdgcn_mov_dpp(__float_as_int(v), 0x4E, 0xF, 0xF, true)));  // quad_perm(2,3,0,1)
    v = fmaxf(v, __int_as_float(__builtin_amdgcn_mov_dpp(__float_as_int(v), 0x141, 0xF, 0xF, true))); // row_half_mirror
    v = fmaxf(v, __int_as_float(__builtin_amdgcn_mov_dpp(__float_as_int(v), 0x140, 0xF, 0xF, true))); // row_mirror
    return v;
}
static __device__ inline float dpp_add16(float v) {
    v += __int_as_float(__builtin_amdgcn_mov_dpp(__float_as_int(v), 0xB1, 0xF, 0xF, true));
    v += __int_as_float(__builtin_amdgcn_mov_dpp(__float_as_int(v), 0x4E, 0xF, 0xF, true));
    v += __int_as_float(__builtin_amdgcn_mov_dpp(__float_as_int(v), 0x141, 0xF, 0xF, true));
    v += __int_as_float(__builtin_amdgcn_mov_dpp(__float_as_int(v), 0x140, 0xF, 0xF, true));
    return v;
}

// ---------------- cast x, w_qkv, w_out to bf16 (one fused launch) -------------
__global__ void cast_all(const float* __restrict__ x,
                         const float* __restrict__ wqkv,
                         const float* __restrict__ wout,
                         unsigned short* __restrict__ xb,
                         unsigned short* __restrict__ wqkvb,
                         unsigned short* __restrict__ woutb) {
    long i4 = (long)(blockIdx.x * blockDim.x + threadIdx.x) * 4;
    const float* src; unsigned short* dst; long off;
    if (i4 < 4194304L)      { src = x;    dst = xb;    off = i4; }
    else if (i4 < 7340032L) { src = wqkv; dst = wqkvb; off = i4 - 4194304L; }
    else                    { src = wout; dst = woutb; off = i4 - 7340032L; }
    float4 v = *(const float4*)(src + off);
    ushort4 o;
    o.x = f2bf(v.x); o.y = f2bf(v.y); o.z = f2bf(v.z); o.w = f2bf(v.w);
    *(ushort4*)(dst + off) = o;
}

// ---------------- GEMM qkv (NT): C[m,n] = sum_k A[m,k]*B[n,k] + bias[n] ------
// 128x128 tile, BK=32, async global_load_lds staging (m97 structure).
#define BK 32

__global__ __launch_bounds__(256, 2) void gemm_qkv(
    const unsigned short* __restrict__ A,   // xb [4096][1024]
    const unsigned short* __restrict__ B,   // wqkvb [3072][1024]
    const float* __restrict__ bias,         // [3072]
    unsigned short* __restrict__ C)         // qkv bf16 [4096][3072]
{
    __shared__ __align__(16) unsigned short sA[128][BK];
    __shared__ __align__(16) unsigned short sB[128][BK];
    const int tid  = threadIdx.x;
    const int wave = tid >> 6, lane = tid & 63;
    const int quad = lane >> 4, l16 = lane & 15;
    const int wm = wave >> 1, wn = wave & 1;
    const int m0 = blockIdx.x * 128, n0 = blockIdx.y * 128;

    const int srow = tid >> 2;   // 0..63
    const int sseg = tid & 3;    // 16B seg

    f32x4 acc[4][4];
    const f32x4 zero = {0.f, 0.f, 0.f, 0.f};
    #pragma unroll
    for (int i = 0; i < 4; i++)
        #pragma unroll
        for (int j = 0; j < 4; j++) acc[i][j] = zero;

    const unsigned short* gA0 = A + (long)(m0 + srow) * 1024 + sseg * 8;
    const unsigned short* gB0 = B + (long)(n0 + srow) * 1024 + sseg * 8;
    unsigned short* lA0 = &sA[wave * 16][0];         // wave-uniform; lane*16B appended by HW
    unsigned short* lA1 = &sA[64 + wave * 16][0];
    unsigned short* lB0 = &sB[wave * 16][0];
    unsigned short* lB1 = &sB[64 + wave * 16][0];

    for (int k0 = 0; k0 < 1024; k0 += BK) {
        __syncthreads();   // previous iteration's LDS reads done
        GLDS(gA0 + k0,               lA0);
        GLDS(gA0 + k0 + 64L * 1024,  lA1);
        GLDS(gB0 + k0,               lB0);
        GLDS(gB0 + k0 + 64L * 1024,  lB1);
        __syncthreads();   // vmcnt drained by barrier semantics
        bf16x8 af[4], bfr[4];
        #pragma unroll
        for (int mt = 0; mt < 4; mt++)
            af[mt] = *(const bf16x8*)(&sA[wm * 64 + mt * 16 + l16][quad * 8]);
        #pragma unroll
        for (int nt = 0; nt < 4; nt++)
            bfr[nt] = *(const bf16x8*)(&sB[wn * 64 + nt * 16 + l16][quad * 8]);
        #pragma unroll
        for (int mt = 0; mt < 4; mt++)
            #pragma unroll
            for (int nt = 0; nt < 4; nt++)
                acc[mt][nt] = __builtin_amdgcn_mfma_f32_16x16x32_bf16(
                    af[mt], bfr[nt], acc[mt][nt], 0, 0, 0);
    }
    #pragma unroll
    for (int nt = 0; nt < 4; nt++) {
        const int n_g = n0 + wn * 64 + nt * 16 + l16;
        const float bv = bias[n_g];
        #pragma unroll
        for (int mt = 0; mt < 4; mt++) {
            #pragma unroll
            for (int r = 0; r < 4; r++) {
                const int m_g = m0 + wm * 64 + mt * 16 + quad * 4 + r;
                C[(long)m_g * N3 + n_g] = f2bf(acc[mt][nt][r] + bv);
            }
        }
    }
}

// ---------------- GEMM out: 128x64 tile (512 blocks -> 2/CU) -----------------
__global__ __launch_bounds__(256, 2) void gemm_out(
    const unsigned short* __restrict__ A,   // attnb [4096][1024]
    const unsigned short* __restrict__ B,   // woutb [1024][1024]
    const float* __restrict__ bias,         // [1024]
    float* __restrict__ C)                  // d_out fp32 [4096][1024]
{
    __shared__ __align__(16) unsigned short sA[128][BK];
    __shared__ __align__(16) unsigned short sB[64][BK];
    const int tid  = threadIdx.x;
    const int wave = tid >> 6, lane = tid & 63;
    const int quad = lane >> 4, l16 = lane & 15;
    const int wm = wave >> 1, wn = wave & 1;
    const int m0 = blockIdx.x * 128, n0 = blockIdx.y * 64;

    const int srow = tid >> 2;
    const int sseg = tid & 3;

    f32x4 acc[4][2];
    const f32x4 zero = {0.f, 0.f, 0.f, 0.f};
    #pragma unroll
    for (int i = 0; i < 4; i++) { acc[i][0] = zero; acc[i][1] = zero; }

    const unsigned short* gA0 = A + (long)(m0 + srow) * 1024 + sseg * 8;
    const unsigned short* gB0 = B + (long)(n0 + srow) * 1024 + sseg * 8;
    unsigned short* lA0 = &sA[wave * 16][0];
    unsigned short* lA1 = &sA[64 + wave * 16][0];
    unsigned short* lB0 = &sB[wave * 16][0];

    for (int k0 = 0; k0 < 1024; k0 += BK) {
        __syncthreads();
        GLDS(gA0 + k0,              lA0);
        GLDS(gA0 + k0 + 64L * 1024, lA1);
        GLDS(gB0 + k0,              lB0);   // only 64 B-rows
        __syncthreads();
        bf16x8 af[4], bfr[2];
        #pragma unroll
        for (int mt = 0; mt < 4; mt++)
            af[mt] = *(const bf16x8*)(&sA[wm * 64 + mt * 16 + l16][quad * 8]);
        #pragma unroll
        for (int nt = 0; nt < 2; nt++)
            bfr[nt] = *(const bf16x8*)(&sB[wn * 32 + nt * 16 + l16][quad * 8]);
        #pragma unroll
        for (int mt = 0; mt < 4; mt++)
            #pragma unroll
            for (int nt = 0; nt < 2; nt++)
                acc[mt][nt] = __builtin_amdgcn_mfma_f32_16x16x32_bf16(
                    af[mt], bfr[nt], acc[mt][nt], 0, 0, 0);
    }
    #pragma unroll
    for (int nt = 0; nt < 2; nt++) {
        const int n_g = n0 + wn * 32 + nt * 16 + l16;
        const float bv = bias[n_g];
        #pragma unroll
        for (int mt = 0; mt < 4; mt++) {
            #pragma unroll
            for (int r = 0; r < 4; r++) {
                const int m_g = m0 + wm * 64 + mt * 16 + quad * 4 + r;
                C[(long)m_g * DMODEL + n_g] = acc[mt][nt][r] + bv;
            }
        }
    }
}

// ---------------- flash attention (causal), double-buffered ------------------
// grid (32 bh, 32 qtiles big-first). 4 waves; wave w owns Q rows qbase+16w..+15.
// One barrier per KV tile; staging loads for t+1 overlap compute of t.
__global__ __launch_bounds__(256, 2) void attn_kernel(
    const unsigned short* __restrict__ qkv,  // [4096][3072] bf16 (q|k|v)
    unsigned short* __restrict__ attn)       // [4096][1024] bf16
{
    __shared__ __align__(16) unsigned short sK[2][64][72];
    __shared__ __align__(16) unsigned short sVt[2][64][72];  // kv-seg XOR-swizzled
    __shared__ __align__(16) unsigned short sP[4][16][72];

    const int tid  = threadIdx.x;
    const int wave = tid >> 6, lane = tid & 63;
    const int quad = lane >> 4, l16 = lane & 15;

    const int bh = blockIdx.x;                     // 0..31
    const int b  = bh >> 4, h = bh & 15;
    const int qtile = (int)gridDim.y - 1 - (int)blockIdx.y;  // big tiles first
    const int qbase = qtile * 64;
    const int ntiles = qtile + 1;

    // Q fragments (A-layout: m=l16, k=quad*8+j)
    bf16x8 qf0, qf1;
    {
        const int qrow = qbase + wave * 16 + l16;
        const unsigned short* qp = qkv + (long)(b * SEQ + qrow) * N3 + h * HDIM;
        qf0 = *(const bf16x8*)(qp + quad * 8);
        qf1 = *(const bf16x8*)(qp + 32 + quad * 8);
    }

    const f32x4 zero = {0.f, 0.f, 0.f, 0.f};
    f32x4 Oacc[4];
    #pragma unroll
    for (int nt = 0; nt < 4; nt++) Oacc[nt] = zero;
    f32x4 m_i = {-1e30f, -1e30f, -1e30f, -1e30f};
    f32x4 l_i = zero;

    // staging index precompute
    const int kr = tid >> 3, ksg = tid & 7;   // K: 32 rows x 8 segs (x2 sweeps)
    const int vr = tid >> 2, vds = tid & 3;   // V: 64 rows x 4 dsegs of 16
    const int vcol = (((vr >> 3) ^ vds) << 3) | (vr & 7);  // swizzled kv position

    const long rowb = (long)b * SEQ;
    const unsigned short* kbase = qkv + DMODEL + h * HDIM + ksg * 8 + (rowb + kr) * N3;
    const unsigned short* vbase = qkv + 2 * DMODEL + h * HDIM + vds * 16 + (rowb + vr) * N3;

    const float C2 = 0.18033688011112042f;   // 0.125 * log2(e)

    // prologue: stage tile 0
    int4 ka, kb, va, vb;
    {
        const unsigned short* kp = kbase;
        ka = *(const int4*)kp; kb = *(const int4*)(kp + 32L * N3);
        const unsigned short* vp = vbase;
        va = *(const int4*)vp; vb = *(const int4*)(vp + 8);
        *(int4*)(&sK[0][kr][ksg * 8])      = ka;
        *(int4*)(&sK[0][kr + 32][ksg * 8]) = kb;
        const unsigned short* pa = (const unsigned short*)&va;
        const unsigned short* pb = (const unsigned short*)&vb;
        #pragma unroll
        for (int j = 0; j < 8; j++) sVt[0][vds * 16 + j][vcol]     = pa[j];
        #pragma unroll
        for (int j = 0; j < 8; j++) sVt[0][vds * 16 + 8 + j][vcol] = pb[j];
    }
    __syncthreads();

    for (int t = 0; t < ntiles; ++t) {
        const int buf = t & 1;
        const bool haveNext = (t + 1 < ntiles);
        int4 nka, nkb, nva, nvb;
        if (haveNext) {   // issue loads for next tile; latency hidden by compute
            const unsigned short* kp = kbase + (long)(t + 1) * 64 * N3;
            nka = *(const int4*)kp; nkb = *(const int4*)(kp + 32L * N3);
            const unsigned short* vp = vbase + (long)(t + 1) * 64 * N3;
            nva = *(const int4*)vp; nvb = *(const int4*)(vp + 8);
        }

        // ---- scores: S = Q K^T (16x64 per wave) ----
        f32x4 sc[4];
        #pragma unroll
        for (int nt = 0; nt < 4; nt++) {
            bf16x8 kf0 = *(const bf16x8*)(&sK[buf][nt * 16 + l16][quad * 8]);
            bf16x8 kf1 = *(const bf16x8*)(&sK[buf][nt * 16 + l16][32 + quad * 8]);
            sc[nt] = __builtin_amdgcn_mfma_f32_16x16x32_bf16(qf0, kf0, zero, 0, 0, 0);
            sc[nt] = __builtin_amdgcn_mfma_f32_16x16x32_bf16(qf1, kf1, sc[nt], 0, 0, 0);
        }
        // ---- causal mask: only the diagonal tile needs it ----
        if (t == qtile) {
            const int wl = wave * 16 + quad * 4;
            #pragma unroll
            for (int nt = 0; nt < 4; nt++) {
                const int co = nt * 16 + l16;
                #pragma unroll
                for (int r = 0; r < 4; r++)
                    if (co > wl + r) sc[nt][r] = -1e30f;
            }
        }
        // ---- online softmax (exp2 domain; scale folded into one FMA) ----
        f32x4 mx01, mx23, mxv;
        #pragma unroll
        for (int r = 0; r < 4; r++) {
            mx01[r] = fmaxf(sc[0][r], sc[1][r]);
            mx23[r] = fmaxf(sc[2][r], sc[3][r]);
            mxv[r]  = fmaxf(mx01[r], mx23[r]);
        }
        f32x4 mnew, al;
        #pragma unroll
        for (int r = 0; r < 4; r++) {
            float mr = dpp_max16(mxv[r]);
            mnew[r] = fmaxf(m_i[r], mr);
            al[r] = __builtin_amdgcn_exp2f((m_i[r] - mnew[r]) * C2);
        }
        const f32x4 cm = mnew * C2;
        f32x4 p[4];
        #pragma unroll
        for (int nt = 0; nt < 4; nt++) {
            f32x4 a = sc[nt] * C2 - cm;
            #pragma unroll
            for (int r = 0; r < 4; r++) p[nt][r] = __builtin_amdgcn_exp2f(a[r]);
        }
        l_i = l_i * al + ((p[0] + p[1]) + (p[2] + p[3]));   // per-lane partial sums
        m_i = mnew;
        #pragma unroll
        for (int nt = 0; nt < 4; nt++) Oacc[nt] *= al;

        // ---- P: C-layout -> A-layout via per-wave LDS round-trip ----
        #pragma unroll
        for (int nt = 0; nt < 4; nt++) {
            union { __hip_bfloat162 h2; unsigned u; } c01, c23;
            c01.h2 = __float22bfloat162_rn(make_float2(p[nt][0], p[nt][1]));
            c23.h2 = __float22bfloat162_rn(make_float2(p[nt][2], p[nt][3]));
            unsigned short* dst = &sP[wave][quad * 4][nt * 16 + l16];
            dst[0]   = (unsigned short)(c01.u);
            dst[72]  = (unsigned short)(c01.u >> 16);
            dst[144] = (unsigned short)(c23.u);
            dst[216] = (unsigned short)(c23.u >> 16);
        }
        bf16x8 pf0 = *(const bf16x8*)(&sP[wave][l16][quad * 8]);
        bf16x8 pf1 = *(const bf16x8*)(&sP[wave][l16][32 + quad * 8]);
        // ---- O += P V ----
        #pragma unroll
        for (int nt = 0; nt < 4; nt++) {
            bf16x8 vf0 = *(const bf16x8*)(&sVt[buf][nt * 16 + l16][(quad ^ nt) * 8]);
            bf16x8 vf1 = *(const bf16x8*)(&sVt[buf][nt * 16 + l16][32 + (quad ^ nt) * 8]);
            Oacc[nt] = __builtin_amdgcn_mfma_f32_16x16x32_bf16(pf0, vf0, Oacc[nt], 0, 0, 0);
            Oacc[nt] = __builtin_amdgcn_mfma_f32_16x16x32_bf16(pf1, vf1, Oacc[nt], 0, 0, 0);
        }

        if (haveNext) {   // write next tile into the other buffer, one barrier
            *(int4*)(&sK[buf ^ 1][kr][ksg * 8])      = nka;
            *(int4*)(&sK[buf ^ 1][kr + 32][ksg * 8]) = nkb;
            const unsigned short* pa = (const unsigned short*)&nva;
            const unsigned short* pb = (const unsigned short*)&nvb;
            #pragma unroll
            for (int j = 0; j < 8; j++) sVt[buf ^ 1][vds * 16 + j][vcol]     = pa[j];
            #pragma unroll
            for (int j = 0; j < 8; j++) sVt[buf ^ 1][vds * 16 + 8 + j][vcol] = pb[j];
            __syncthreads();
        }
    }
    // ---- epilogue: attn[b, row, h*64+d] = O / l ----
    const int rowg = qbase + wave * 16 + quad * 4;
    #pragma unroll
    for (int r = 0; r < 4; r++) {
        const float L = dpp_add16(l_i[r]);
        const float inv = 1.0f / L;
        #pragma unroll
        for (int nt = 0; nt < 4; nt++)
            attn[(long)(b * SEQ + rowg + r) * DMODEL + h * HDIM + nt * 16 + l16] =
                f2bf(Oacc[nt][r] * inv);
    }
}

// -----------------------------------------------------------------------------
extern "C" void kernel_launch(void* const* d_in, const int* in_sizes, int n_in,
                              void* d_out, int out_size, void* d_ws, size_t ws_size,
                              hipStream_t stream) {
    const float* x    = (const float*)d_in[0];
    const float* wqkv = (const float*)d_in[1];
    const float* bqkv = (const float*)d_in[2];
    const float* wout = (const float*)d_in[3];
    const float* bout = (const float*)d_in[4];

    char* ws = (char*)d_ws;
    unsigned short* xb    = (unsigned short*)(ws);                       //  8.0 MiB
    unsigned short* wqkvb = (unsigned short*)(ws + 8388608);             //  6.0 MiB
    unsigned short* woutb = (unsigned short*)(ws + 14680064);            //  2.0 MiB
    unsigned short* qkvb  = (unsigned short*)(ws + 16777216);            // 24.0 MiB
    unsigned short* attnb = (unsigned short*)(ws + 41943040);            //  8.0 MiB

    cast_all<<<8192, 256, 0, stream>>>(x, wqkv, wout, xb, wqkvb, woutb);

    dim3 g1(32, 24);   // M/128, N3/128
    gemm_qkv<<<g1, 256, 0, stream>>>(xb, wqkvb, bqkv, qkvb);

    dim3 g2(32, 32);   // bh, qtiles (big-first via reversal)
    attn_kernel<<<g2, 256, 0, stream>>>(qkvb, attnb);

    dim3 g3(32, 16);   // M/128, DMODEL/64
    gemm_out<<<g3, 256, 0, stream>>>(attnb, woutb, bout, (float*)d_out);
}